// Round 4
// baseline (5037.179 us; speedup 1.0000x reference)
//
#include <hip/hip_runtime.h>

#define KP   2176   // padded K: 2048 h + 69 x + pad
#define H    2048
#define IN   69
#define TGT  50
#define NKT  68     // K-tiles of 32

typedef unsigned short ushort_t;
typedef __attribute__((ext_vector_type(8))) short  short8;
typedef __attribute__((ext_vector_type(4))) float  float4_t;

__device__ __forceinline__ ushort_t f2bf(float f) {
  union { float f; unsigned u; } v; v.f = f;
  unsigned u = v.u;
  return (ushort_t)((u + 0x7fffu + ((u >> 16) & 1u)) >> 16);
}

template <int N> __device__ __forceinline__ void waitv() {
  asm volatile("s_waitcnt vmcnt(%0)" :: "n"(N) : "memory");
}
#define BAR() __builtin_amdgcn_s_barrier()

// ================= fragment-major layouts =================
// W2[ct 0..63][kt 0..67][g 0..2][wc 0..1][lane 0..63][16B]  (26.7 MB)
//   lane&15 -> output col c = ct*32 + wc*16 + (lane&15); lane>>4 -> k-quarter;
//   fused row: [W_hh[g*2048+c] (k<2048) | W_ih[g*2048+c] (2048<=k<2117) | 0]
// A2[mb 0..31][kt 0..67][lane 0..63][16B]                   (2.23 MB per parity)
//   lane&15 -> m-row (m = mb*16 + (lane&15)); lane>>4 -> k-quarter.
// These match the 16x16x32 MFMA operand mapping exactly -> 1KB coalesced loads.

__global__ void build_w2(const float* __restrict__ Whh, const float* __restrict__ Wih,
                         ushort_t* __restrict__ W2) {
  int i = blockIdx.x * 256 + threadIdx.x;      // 6528*256 = 1,671,168 = 64*68*3*2*64
  int lane = i & 63;
  int wc = (i >> 6) & 1;
  int g  = (i >> 7) % 3;
  int kt = (i / 384) % NKT;
  int ct = i / 26112;
  int c  = ct * 32 + wc * 16 + (lane & 15);
  int gr = g * H + c;
  int k0 = kt * 32 + (lane >> 4) * 8;
  ushort_t v[8];
  #pragma unroll
  for (int j = 0; j < 8; ++j) {
    int k = k0 + j;
    float val = 0.f;
    if (k < H) val = Whh[(size_t)gr * H + k];
    else if (k < H + IN) val = Wih[(size_t)gr * IN + (k - H)];
    v[j] = f2bf(val);
  }
  #pragma unroll
  for (int j = 0; j < 8; ++j) W2[(size_t)i * 8 + j] = v[j];
}

// F2[kt 0..63][ni 0..4][lane][16B]  (327,680 B): col j = ni*16+(lane&15), rows of fc1_w
__global__ void build_f2(const float* __restrict__ fc1w, ushort_t* __restrict__ F2) {
  int i = blockIdx.x * 256 + threadIdx.x;      // 80*256 = 20480 = 64*5*64
  int lane = i & 63;
  int ni = (i >> 6) % 5;
  int kt = i / 320;
  int j  = ni * 16 + (lane & 15);
  int k0 = kt * 32 + (lane >> 4) * 8;
  ushort_t v[8];
  #pragma unroll
  for (int jj = 0; jj < 8; ++jj) {
    float val = (j < IN) ? fc1w[(size_t)j * H + k0 + jj] : 0.f;
    v[jj] = f2bf(val);
  }
  #pragma unroll
  for (int jj = 0; jj < 8; ++jj) F2[(size_t)i * 8 + jj] = v[jj];
}

__global__ void zero_u4(uint4* p, int n) {
  int i = blockIdx.x * 256 + threadIdx.x;
  if (i < n) p[i] = make_uint4(0, 0, 0, 0);
}

// x[b][j] -> A2 at k = 2048+j
__device__ __forceinline__ size_t a2_x_off(int b, int j) {
  int k = 2048 + j;
  int kt = k >> 5, kk = k & 31;
  int mb = b >> 4;
  int ln = (b & 15) | ((kk >> 3) << 4);
  return ((size_t)(mb * NKT + kt) * 64 + ln) * 16 + (kk & 7) * 2;
}

__global__ void fill_x0(const float* __restrict__ enc, char* __restrict__ A2) {
  int i = blockIdx.x * 256 + threadIdx.x;  // 512*69
  int b = i / IN, j = i - b * IN;
  *(ushort_t*)(A2 + a2_x_off(b, j)) = f2bf(enc[(size_t)b * 100 * IN + j]);
}

// ================= fused GRU step (no LDS, no syncthreads) =================
// grid = 256 (xcd-major -> ct 0..63, mt 0..3), block = 256 = 4 waves (wm x wc).
// Per wave: depth-4 per-wave pipeline of 7 coalesced dwordx4 loads + 12 MFMA per k-tile.
__global__ __launch_bounds__(256, 1) void gru_step(
    const char* __restrict__ Aprev, char* __restrict__ Anext,
    const char* __restrict__ W2, float* __restrict__ h32,
    const float* __restrict__ b_ih, const float* __restrict__ b_hh,
    const float* __restrict__ xsrc, int xstride)
{
  const int tid = threadIdx.x;
  const int bid = blockIdx.x;
  const int xcd = bid & 7, slot = bid >> 3;
  const int ct = xcd * 8 + (slot & 7);   // B-slice per XCD = 3.34 MB (L2 locality)
  const int mt = slot >> 3;              // 0..3, BM=128
  const int lane = tid & 63, w = tid >> 6;
  const int l15 = lane & 15, l4 = lane >> 4;
  const int wm = w & 1, wc = w >> 1;

  const char* Ap[4];
  #pragma unroll
  for (int mi = 0; mi < 4; ++mi)
    Ap[mi] = Aprev + ((size_t)(mt * 8 + wm * 4 + mi) * NKT) * 1024 + lane * 16;
  const char* Bp[3];
  #pragma unroll
  for (int g = 0; g < 3; ++g)
    Bp[g] = W2 + ((size_t)(ct * NKT) * 6 + g * 2 + wc) * 1024 + lane * 16;

  short8 fa[4][4], fb[4][3];
  float4_t acc[4][4] = {};  // [mi][r, z, gh_n, gi_n]

#define LOADT(d, kt) \
  fa[d][0] = *(const short8*)(Ap[0] + (kt) * 1024); \
  fa[d][1] = *(const short8*)(Ap[1] + (kt) * 1024); \
  fa[d][2] = *(const short8*)(Ap[2] + (kt) * 1024); \
  fa[d][3] = *(const short8*)(Ap[3] + (kt) * 1024); \
  fb[d][0] = *(const short8*)(Bp[0] + (kt) * 6144); \
  fb[d][1] = *(const short8*)(Bp[1] + (kt) * 6144); \
  fb[d][2] = *(const short8*)(Bp[2] + (kt) * 6144);

#define MFMAT(d, G2) \
  { _Pragma("unroll") \
    for (int mi = 0; mi < 4; ++mi) { \
      acc[mi][0]  = __builtin_amdgcn_mfma_f32_16x16x32_bf16(fa[d][mi], fb[d][0], acc[mi][0], 0, 0, 0); \
      acc[mi][1]  = __builtin_amdgcn_mfma_f32_16x16x32_bf16(fa[d][mi], fb[d][1], acc[mi][1], 0, 0, 0); \
      acc[mi][G2] = __builtin_amdgcn_mfma_f32_16x16x32_bf16(fa[d][mi], fb[d][2], acc[mi][G2], 0, 0, 0); \
    } }

#define PROC(d, kt) { waitv<21>(); BAR(); MFMAT(d, 2); LOADT(d, (kt) + 4); }

  LOADT(0, 0); LOADT(1, 1); LOADT(2, 2); LOADT(3, 3);
  for (int kt = 0; kt < 64; kt += 4) {
    PROC(0, kt); PROC(1, kt + 1); PROC(2, kt + 2); PROC(3, kt + 3);
  }
  // tail: k-tiles 64..67 are the x-part -> g2 product goes to acc[3] (gi_n)
  waitv<21>(); BAR(); MFMAT(0, 3);
  waitv<14>(); BAR(); MFMAT(1, 3);
  waitv<7>();  BAR(); MFMAT(2, 3);
  waitv<0>();  BAR(); MFMAT(3, 3);

  // epilogue: gates fp32, fp32 carry, bf16 h -> fragment-major Anext
  const int c = ct * 32 + wc * 16 + l15;
  const float br  = b_ih[c] + b_hh[c];
  const float bz  = b_ih[H + c] + b_hh[H + c];
  const float bin = b_ih[2 * H + c];
  const float bhn = b_hh[2 * H + c];
  const int ktc = c >> 5;
  const int laneHi = ((c >> 3) & 3) << 4;
  const int byteOff = (c & 7) * 2;
  #pragma unroll
  for (int mi = 0; mi < 4; ++mi) {
    const int mb = mt * 8 + wm * 4 + mi;
    char* dst = Anext + ((size_t)(mb * NKT + ktc) * 64 + laneHi) * 16 + byteOff;
    #pragma unroll
    for (int r4 = 0; r4 < 4; ++r4) {
      int mlo = l4 * 4 + r4;
      int m = mt * 128 + wm * 64 + mi * 16 + mlo;
      float rg = 1.f / (1.f + __expf(-(acc[mi][0][r4] + br)));
      float zg = 1.f / (1.f + __expf(-(acc[mi][1][r4] + bz)));
      float ng = tanhf(acc[mi][3][r4] + bin + rg * (acc[mi][2][r4] + bhn));
      float hold = h32[(size_t)m * H + c];
      float hn = (1.f - zg) * ng + zg * hold;
      h32[(size_t)m * H + c] = hn;
      *(ushort_t*)(dst + mlo * 16) = f2bf(hn);
    }
  }
  // encoder next-x copy (ct==0 WGs: mt 0..3 cover all 512 rows)
  if (ct == 0 && xsrc != nullptr) {
    for (int i = tid; i < 128 * IN; i += 256) {
      int rr = i / IN, cc = i - rr * IN;
      int b = mt * 128 + rr;
      *(ushort_t*)(Anext + a2_x_off(b, cc)) = f2bf(xsrc[(size_t)b * xstride + cc]);
    }
  }
}

// ================= decoder output step (no LDS) =================
// out[m,j] = inp[m,j] + h[m,:] @ fc1_w[j,:] + fc1_b[j]; j<69, K=2048 (k-tiles 0..63)
__global__ __launch_bounds__(256, 1) void out_step(
    char* Acat,                            // A2 parity: read h-part, write x-part
    const char* __restrict__ F2,
    const float* __restrict__ fc1_bias,
    const float* __restrict__ inp,         // row stride TGT*IN
    float* __restrict__ outp)              // d_out + d*IN, row stride TGT*IN
{
  const int tid = threadIdx.x;
  const int lane = tid & 63, w = tid >> 6;
  const int l15 = lane & 15, l4 = lane >> 4;
  const int mb = blockIdx.x * 4 + w;       // 0..31

  const char* Ap = Acat + (size_t)mb * NKT * 1024 + lane * 16;
  const char* Bp = F2 + lane * 16;

  short8 fa[4]; short8 fb[4][5];
  float4_t acc[5] = {};

#define OLOAD(d, kt) \
  fa[d]    = *(const short8*)(Ap + (kt) * 1024); \
  fb[d][0] = *(const short8*)(Bp + (kt) * 5120); \
  fb[d][1] = *(const short8*)(Bp + (kt) * 5120 + 1024); \
  fb[d][2] = *(const short8*)(Bp + (kt) * 5120 + 2048); \
  fb[d][3] = *(const short8*)(Bp + (kt) * 5120 + 3072); \
  fb[d][4] = *(const short8*)(Bp + (kt) * 5120 + 4096);

#define OMFMA(d) \
  { _Pragma("unroll") \
    for (int ni = 0; ni < 5; ++ni) \
      acc[ni] = __builtin_amdgcn_mfma_f32_16x16x32_bf16(fa[d], fb[d][ni], acc[ni], 0, 0, 0); }

#define OPROC(d, kt) { waitv<18>(); OMFMA(d); OLOAD(d, (kt) + 4); }

  OLOAD(0, 0); OLOAD(1, 1); OLOAD(2, 2); OLOAD(3, 3);
  for (int kt = 0; kt < 60; kt += 4) {
    OPROC(0, kt); OPROC(1, kt + 1); OPROC(2, kt + 2); OPROC(3, kt + 3);
  }
  waitv<18>(); OMFMA(0);
  waitv<12>(); OMFMA(1);
  waitv<6>();  OMFMA(2);
  waitv<0>();  OMFMA(3);

  #pragma unroll
  for (int ni = 0; ni < 5; ++ni) {
    int j = ni * 16 + l15;
    if (j < IN) {
      float bj = fc1_bias[j];
      #pragma unroll
      for (int r4 = 0; r4 < 4; ++r4) {
        int m = mb * 16 + l4 * 4 + r4;
        float v = acc[ni][r4] + bj + inp[(size_t)m * (TGT * IN) + j];
        outp[(size_t)m * (TGT * IN) + j] = v;
        *(ushort_t*)(Acat + a2_x_off(m, j)) = f2bf(v);   // next decoder input
      }
    }
  }
}

// ================= launch =================
extern "C" void kernel_launch(void* const* d_in, const int* in_sizes, int n_in,
                              void* d_out, int out_size, void* d_ws, size_t ws_size,
                              hipStream_t stream) {
  const float* enc  = (const float*)d_in[0];
  const float* dec  = (const float*)d_in[1];
  const float* Wih  = (const float*)d_in[2];
  const float* Whh  = (const float*)d_in[3];
  const float* b_ih = (const float*)d_in[4];
  const float* b_hh = (const float*)d_in[5];
  const float* fc1w = (const float*)d_in[6];
  const float* fc1b = (const float*)d_in[7];
  float* out = (float*)d_out;

  char* ws = (char*)d_ws;
  ushort_t* W2  = (ushort_t*)(ws);                 // 26,738,688
  char*     A2_0 = ws + 26738688;                  // 2,228,224
  char*     A2_1 = ws + 28966912;                  // 2,228,224
  float*    h32  = (float*)(ws + 31195136);        // 4,194,304
  ushort_t* F2   = (ushort_t*)(ws + 35389440);     // 327,680
  char* A2[2] = {A2_0, A2_1};

  build_w2<<<6528, 256, 0, stream>>>(Whh, Wih, W2);
  zero_u4<<<2112, 256, 0, stream>>>((uint4*)A2_0, 540672);  // A2_0 + A2_1 + h32
  fill_x0<<<138, 256, 0, stream>>>(enc, A2_0);
  build_f2<<<80, 256, 0, stream>>>(fc1w, F2);

  for (int t = 0; t < 149; ++t) {
    const float* xsrc = nullptr; int xstride = 0;
    if (t < 98)       { xsrc = enc + (size_t)(t + 1) * IN; xstride = 100 * IN; }
    else if (t == 98) { xsrc = dec;                        xstride = TGT * IN; }
    gru_step<<<256, 256, 0, stream>>>(A2[t & 1], A2[(t + 1) & 1], (const char*)W2, h32,
                                      b_ih, b_hh, xsrc, xstride);
    if (t >= 99) {
      int d = t - 99;
      const float* inp = (d == 0) ? dec : out + (size_t)(d - 1) * IN;
      out_step<<<8, 256, 0, stream>>>(A2[(t + 1) & 1], (const char*)F2, fc1b, inp,
                                      out + (size_t)d * IN);
    }
  }
}

// Round 7
// 4193.233 us; speedup vs baseline: 1.2013x; 1.2013x over previous
//
#include <hip/hip_runtime.h>

#define KP   2176
#define H    2048
#define IN   69
#define TGT  50
#define NKT  68     // K-tiles of 32 (2048 h + 69 x + pad)

typedef unsigned short ushort_t;
typedef unsigned int   uint_t;
typedef __attribute__((ext_vector_type(8))) short  short8;
typedef __attribute__((ext_vector_type(4))) float  float4_t;

#define MFMA_BF16 __builtin_amdgcn_mfma_f32_16x16x32_bf16

__device__ __forceinline__ ushort_t f2bf(float f) {
  union { float f; unsigned u; } v; v.f = f;
  unsigned u = v.u;
  return (ushort_t)((u + 0x7fffu + ((u >> 16) & 1u)) >> 16);
}

template <int N> __device__ __forceinline__ void waitv() {
  asm volatile("s_waitcnt vmcnt(%0)" :: "n"(N) : "memory");
}
#define SGB0() __builtin_amdgcn_sched_barrier(0)

// plain load (coherence via dispatch boundaries — proven r1-r4)
template <int OFF> __device__ __forceinline__ void gld(short8& d, uint_t voff, const void* base) {
  asm volatile("global_load_dwordx4 %0, %1, %2 offset:%3"
               : "=v"(d) : "v"(voff), "s"(base), "n"(OFF));
}

// ================= fragment-major layouts =================
// W3[rb 0..383][kt 0..67][lane][16B], rb = cb*3 + g (cb = 16-col block, g = gate):
//   col c = cb*16 + (lane&15); fused row = [W_hh[g*2048+c] (k<2048) | W_ih[...] | 0]
// A2[mb 0..31][kt 0..67][lane][16B]: lane&15 -> m-row, lane>>4 -> k-quarter.
// F2[kt 0..63][nf 0..4][lane][16B]: fc1 cols j = nf*16 + (lane&15).

__global__ void build_w3(const float* __restrict__ Whh, const float* __restrict__ Wih,
                         ushort_t* __restrict__ W3) {
  int i = blockIdx.x * 256 + threadIdx.x;   // 6528*256 = 1,671,168 = 384*68*64
  int lane = i & 63;
  int kt = (i >> 6) % NKT;
  int rb = i / (64 * NKT);                  // 0..383
  int cb = rb / 3, g = rb - cb * 3;
  int c  = cb * 16 + (lane & 15);
  int gr = g * H + c;
  int k0 = kt * 32 + (lane >> 4) * 8;
  short8 v;
  #pragma unroll
  for (int j = 0; j < 8; ++j) {
    int k = k0 + j;
    float val = 0.f;
    if (k < H) val = Whh[(size_t)gr * H + k];
    else if (k < H + IN) val = Wih[(size_t)gr * IN + (k - H)];
    v[j] = (short)f2bf(val);
  }
  *(short8*)(W3 + (size_t)i * 8) = v;
}

__global__ void build_f2(const float* __restrict__ fc1w, ushort_t* __restrict__ F2) {
  int i = blockIdx.x * 256 + threadIdx.x;   // 80*256 = 20480 = 64*5*64
  int lane = i & 63;
  int ni = (i >> 6) % 5;
  int kt = i / 320;
  int j  = ni * 16 + (lane & 15);
  int k0 = kt * 32 + (lane >> 4) * 8;
  short8 v;
  #pragma unroll
  for (int jj = 0; jj < 8; ++jj) {
    float val = (j < IN) ? fc1w[(size_t)j * H + k0 + jj] : 0.f;
    v[jj] = (short)f2bf(val);
  }
  *(short8*)(F2 + (size_t)i * 8) = v;
}

__global__ void zero_u4(uint4* p, int n) {
  int i = blockIdx.x * 256 + threadIdx.x;
  if (i < n) p[i] = make_uint4(0, 0, 0, 0);
}

__device__ __forceinline__ size_t a2_x_off(int b, int j) {
  int k = 2048 + j;
  int kt = k >> 5, kk = k & 31;
  int mb = b >> 4;
  int ln = (b & 15) | ((kk >> 3) << 4);
  return ((size_t)(mb * NKT + kt) * 64 + ln) * 16 + (kk & 7) * 2;
}

__global__ void fill_x0(const float* __restrict__ enc, char* __restrict__ A2) {
  int i = blockIdx.x * 256 + threadIdx.x;   // 512*69
  int b = i / IN, j = i - b * IN;
  *(ushort_t*)(A2 + a2_x_off(b, j)) = f2bf(enc[(size_t)b * 100 * IN + j]);
}

// ================= fused GRU step =================
// grid 256: cg = (bid&7)*4 + ((bid>>3)&3) (0..31, 64 cols), mt = bid>>5 (BM=64).
// Wave w: cb = cg*4 + w (16 cols x 3 gates, B wave-unique); A: all 4 mb, shared via L1.
// Depth-8 dual-stream register pipeline; EXACT issue (68 tiles) and EXACT drain
// (waitv<0> before epilogue) — no outstanding loads may survive into register reuse.
__global__ __launch_bounds__(256, 1) void gru_step(
    const char* __restrict__ Aprev, char* __restrict__ Anext,
    const char* __restrict__ W3p, float* __restrict__ h32,
    const float* __restrict__ bih, const float* __restrict__ bhh,
    const float* __restrict__ xsrc, int xstride)
{
  __shared__ __align__(16) char ldsbuf[90112];   // 88KB: forces 1 WG/CU; epilogue uses 9216B
  ushort_t (*smh)[72] = (ushort_t (*)[72])ldsbuf;

  const int tid = threadIdx.x;
  const int bid = blockIdx.x;
  const int lane = tid & 63, w = tid >> 6;
  const int l15 = lane & 15, l4 = lane >> 4;
  const int cg = (bid & 7) * 4 + ((bid >> 3) & 3);
  const int mt = bid >> 5;
  const int cb = cg * 4 + w;
  const int c  = cb * 16 + l15;

  const float br  = bih[c] + bhh[c];
  const float bz  = bih[H + c] + bhh[H + c];
  const float bin = bih[2 * H + c];
  const float bhn = bhh[2 * H + c];
  // force bias loads resolved before the asm pipeline starts (keeps vmcnt stream clean)
  asm volatile("" :: "v"(br), "v"(bz), "v"(bin), "v"(bhn));

  const void* ApB0 = Aprev + (size_t)(mt * 4 + 0) * (NKT * 1024);
  const void* ApB1 = Aprev + (size_t)(mt * 4 + 1) * (NKT * 1024);
  const void* ApB2 = Aprev + (size_t)(mt * 4 + 2) * (NKT * 1024);
  const void* ApB3 = Aprev + (size_t)(mt * 4 + 3) * (NKT * 1024);
  uint_t vA  = (uint_t)(lane * 16);
  uint_t vB0 = (uint_t)((cb * 3 + 0) * (NKT * 1024) + lane * 16);
  uint_t vB1 = (uint_t)((cb * 3 + 1) * (NKT * 1024) + lane * 16);
  uint_t vB2 = (uint_t)((cb * 3 + 2) * (NKT * 1024) + lane * 16);

  short8 fa[8][4], fb[8][3];
  float4_t acc[4][4] = {};   // [mi][r, z, gh_n, gi_n]

#define ISSB(sl) \
  gld<0>(fb[sl][0], vB0, W3p); gld<0>(fb[sl][1], vB1, W3p); gld<0>(fb[sl][2], vB2, W3p); \
  vB0 += 1024; vB1 += 1024; vB2 += 1024;
#define ISSA(sl) \
  gld<0>(fa[sl][0], vA, ApB0); gld<0>(fa[sl][1], vA, ApB1); \
  gld<0>(fa[sl][2], vA, ApB2); gld<0>(fa[sl][3], vA, ApB3); \
  vA += 1024;
#define MFMAS(j, G2) \
  { _Pragma("unroll") \
    for (int mi = 0; mi < 4; ++mi) { \
      acc[mi][0]  = MFMA_BF16(fa[j][mi], fb[j][0], acc[mi][0], 0, 0, 0); \
      acc[mi][1]  = MFMA_BF16(fa[j][mi], fb[j][1], acc[mi][1], 0, 0, 0); \
      acc[mi][G2] = MFMA_BF16(fa[j][mi], fb[j][2], acc[mi][G2], 0, 0, 0); } }
// steady sub-iter: retire slot j's 7 loads (49 stay in flight), MFMA, reissue slot j.
#define GSUB(j, G2)  waitv<49>(); SGB0(); MFMAS(j, G2) ISSB(j) ISSA(j)
// tail sub-iter: retire with descending count, NO reissue.
#define GSUBT(j, G2, N)  waitv<N>(); SGB0(); MFMAS(j, G2)

  // prologue: tiles 0..7 in flight (56 loads)
  ISSB(0) ISSA(0) ISSB(1) ISSA(1) ISSB(2) ISSA(2) ISSB(3) ISSA(3)
  ISSB(4) ISSA(4) ISSB(5) ISSA(5) ISSB(6) ISSA(6) ISSB(7) ISSA(7)

  #pragma unroll 1
  for (int s0 = 0; s0 < 56; s0 += 8) {   // tiles 0..55 (reissue tiles 8..63)
    GSUB(0, 2) GSUB(1, 2) GSUB(2, 2) GSUB(3, 2)
    GSUB(4, 2) GSUB(5, 2) GSUB(6, 2) GSUB(7, 2)
  }
  // tiles 56..59: reissue slots 0..3 with tiles 64..67 (the last real tiles)
  GSUB(0, 2) GSUB(1, 2) GSUB(2, 2) GSUB(3, 2)
  // tiles 60..63 (h-part) then 64..67 (x-part -> gi_n); drain exactly to 0
  GSUBT(4, 2, 49) GSUBT(5, 2, 42) GSUBT(6, 2, 35) GSUBT(7, 2, 28)
  GSUBT(0, 3, 21) GSUBT(1, 3, 14) GSUBT(2, 3, 7)  GSUBT(3, 3, 0)
  // vmcnt == 0 here: no outstanding asm loads can clobber reused registers below.

  // ---- epilogue: gates fp32, fp32 carry; h' -> LDS transpose -> 16B stores ----
  #pragma unroll
  for (int mi = 0; mi < 4; ++mi) {
    #pragma unroll
    for (int r4 = 0; r4 < 4; ++r4) {
      int m = mt * 64 + mi * 16 + l4 * 4 + r4;
      float rg = 1.f / (1.f + __expf(-(acc[mi][0][r4] + br)));
      float zg = 1.f / (1.f + __expf(-(acc[mi][1][r4] + bz)));
      float ng = tanhf(acc[mi][3][r4] + bin + rg * (acc[mi][2][r4] + bhn));
      float hold = h32[(size_t)m * H + c];
      float hn = (1.f - zg) * ng + zg * hold;
      h32[(size_t)m * H + c] = hn;
      smh[mi * 16 + l4 * 4 + r4][w * 16 + l15] = f2bf(hn);
    }
  }
  __syncthreads();
  #pragma unroll
  for (int e = 0; e < 2; ++e) {
    int cid = tid * 2 + e;                 // 512 chunks: (m 0..63) x (ktrel 0..1) x (khi 0..3)
    int m = cid >> 3, ktrel = (cid >> 2) & 1, khi = cid & 3;
    short8 v = *(const short8*)&smh[m][ktrel * 32 + khi * 8];
    int m_abs = mt * 64 + m;
    int mb2 = m_abs >> 4;
    int ln = (m_abs & 15) | (khi << 4);
    int kt = cg * 2 + ktrel;
    *(short8*)(Anext + ((size_t)(mb2 * NKT + kt) * 64 + ln) * 16) = v;
  }
  // encoder next-x feed (8 WGs with cg==0: mt 0..7 cover all 512 rows)
  if ((bid & 31) == 0 && xsrc != nullptr) {
    for (int i = tid; i < 64 * IN; i += 256) {
      int rr = i / IN, cc = i - rr * IN;
      int m = mt * 64 + rr;
      *(ushort_t*)(Anext + a2_x_off(m, cc)) = f2bf(xsrc[(size_t)m * xstride + cc]);
    }
  }
}

// ================= decoder output step =================
// grid 32 (WG per 16-row block), 4 waves K-split (16 kt each), depth-8 pipeline
// (exact: 16 real tiles/wave, drains to 0), LDS cross-wave reduce.
__global__ __launch_bounds__(256, 1) void out_step(
    char* __restrict__ Acat, const char* __restrict__ F2p,
    const float* __restrict__ fc1b, const float* __restrict__ inp,
    float* __restrict__ outp)
{
  __shared__ float4_t redf[4 * 5 * 64];    // 20KB
  const int tid = threadIdx.x;
  const int mb = blockIdx.x;               // 0..31
  const int lane = tid & 63, w = tid >> 6;
  const int l15 = lane & 15, l4 = lane >> 4;

  const void* F2b = (const char*)F2p + 4096;   // imm offset max 4095 -> second base
  uint_t voA = (uint_t)((mb * NKT + w * 16) * 1024 + lane * 16);
  uint_t vf  = (uint_t)((w * 16) * 5120 + lane * 16);

  short8 da[8], db[8][5];
  float4_t oa[5] = {};

#define DPRO(sl) \
  gld<0>(da[sl], voA, Acat); \
  gld<0>(db[sl][0], vf, F2p); gld<1024>(db[sl][1], vf, F2p); \
  gld<2048>(db[sl][2], vf, F2p); gld<3072>(db[sl][3], vf, F2p); \
  gld<0>(db[sl][4], vf, F2b); \
  voA += 1024; vf += 5120;
#define DMM(sl) \
  { _Pragma("unroll") for (int nf = 0; nf < 5; ++nf) \
      oa[nf] = MFMA_BF16(da[sl], db[sl][nf], oa[nf], 0, 0, 0); }

  DPRO(0) DPRO(1) DPRO(2) DPRO(3) DPRO(4) DPRO(5) DPRO(6) DPRO(7)
  waitv<42>(); SGB0(); DMM(0) DPRO(0)
  waitv<42>(); SGB0(); DMM(1) DPRO(1)
  waitv<42>(); SGB0(); DMM(2) DPRO(2)
  waitv<42>(); SGB0(); DMM(3) DPRO(3)
  waitv<42>(); SGB0(); DMM(4) DPRO(4)
  waitv<42>(); SGB0(); DMM(5) DPRO(5)
  waitv<42>(); SGB0(); DMM(6) DPRO(6)
  waitv<42>(); SGB0(); DMM(7) DPRO(7)
  waitv<42>(); SGB0(); DMM(0)
  waitv<36>(); SGB0(); DMM(1)
  waitv<30>(); SGB0(); DMM(2)
  waitv<24>(); SGB0(); DMM(3)
  waitv<18>(); SGB0(); DMM(4)
  waitv<12>(); SGB0(); DMM(5)
  waitv<6>();  SGB0(); DMM(6)
  waitv<0>();  SGB0(); DMM(7)
  // vmcnt == 0: pipeline fully drained before register reuse below.

  #pragma unroll
  for (int nf = 0; nf < 5; ++nf) redf[(w * 5 + nf) * 64 + lane] = oa[nf];
  __syncthreads();

  #pragma unroll 1
  for (int pass = 0; pass < 2; ++pass) {
    if (pass == 1 && w != 0) break;
    const int nf = pass ? 4 : w;
    float4_t sum = redf[(0 * 5 + nf) * 64 + lane] + redf[(1 * 5 + nf) * 64 + lane]
                 + redf[(2 * 5 + nf) * 64 + lane] + redf[(3 * 5 + nf) * 64 + lane];
    int j = nf * 16 + l15;
    if (j < IN) {
      float bj = fc1b[j];
      #pragma unroll
      for (int r4 = 0; r4 < 4; ++r4) {
        int m = mb * 16 + l4 * 4 + r4;
        float v = sum[r4] + bj + inp[(size_t)m * (TGT * IN) + j];
        outp[(size_t)m * (TGT * IN) + j] = v;
        *(ushort_t*)(Acat + a2_x_off(m, j)) = f2bf(v);   // next decoder input
      }
    }
  }
}

// ================= launch =================
extern "C" void kernel_launch(void* const* d_in, const int* in_sizes, int n_in,
                              void* d_out, int out_size, void* d_ws, size_t ws_size,
                              hipStream_t stream) {
  const float* enc  = (const float*)d_in[0];
  const float* dec  = (const float*)d_in[1];
  const float* Wih  = (const float*)d_in[2];
  const float* Whh  = (const float*)d_in[3];
  const float* b_ih = (const float*)d_in[4];
  const float* b_hh = (const float*)d_in[5];
  const float* fc1w = (const float*)d_in[6];
  const float* fc1b = (const float*)d_in[7];
  float* out = (float*)d_out;

  char* ws = (char*)d_ws;
  ushort_t* W3  = (ushort_t*)ws;                    // 384*68*64*16 = 26,738,688
  char*     A0  = ws + 26738688;                    // 2,228,224
  char*     A1  = ws + 28966912;                    // 2,228,224
  float*    h32 = (float*)(ws + 31195136);          // 4,194,304
  ushort_t* F2  = (ushort_t*)(ws + 35389440);       // 327,680
  char* A2[2] = {A0, A1};

  build_w3<<<6528, 256, 0, stream>>>(Whh, Wih, W3);
  zero_u4<<<2112, 256, 0, stream>>>((uint4*)A0, 540672);   // A0 + A1 + h32
  fill_x0<<<138, 256, 0, stream>>>(enc, A0);
  build_f2<<<80, 256, 0, stream>>>(fc1w, F2);

  for (int t = 0; t < 149; ++t) {
    const float* xsrc = nullptr; int xstride = 0;
    if (t < 98)       { xsrc = enc + (size_t)(t + 1) * IN; xstride = 100 * IN; }
    else if (t == 98) { xsrc = dec;                        xstride = TGT * IN; }
    gru_step<<<256, 256, 0, stream>>>(A2[t & 1], A2[(t + 1) & 1], (const char*)W3, h32,
                                      b_ih, b_hh, xsrc, xstride);
    if (t >= 99) {
      int d = t - 99;
      const float* inp = (d == 0) ? dec : out + (size_t)(d - 1) * IN;
      out_step<<<32, 256, 0, stream>>>(A2[(t + 1) & 1], (const char*)F2, fc1b, inp,
                                       out + (size_t)d * IN);
    }
  }
}

// Round 10
// 4024.062 us; speedup vs baseline: 1.2518x; 1.0420x over previous
//
#include <hip/hip_runtime.h>

#define KP   2176
#define H    2048
#define IN   69
#define TGT  50
#define NKT  68     // K-tiles of 32 (2048 h + 69 x + pad)

typedef unsigned short ushort_t;
typedef unsigned int   uint_t;
typedef __attribute__((ext_vector_type(8))) short  short8;
typedef __attribute__((ext_vector_type(4))) float  float4_t;

#define MFMA_BF16 __builtin_amdgcn_mfma_f32_16x16x32_bf16

__device__ __forceinline__ ushort_t f2bf(float f) {
  union { float f; unsigned u; } v; v.f = f;
  unsigned u = v.u;
  return (ushort_t)((u + 0x7fffu + ((u >> 16) & 1u)) >> 16);
}

template <int N> __device__ __forceinline__ void waitv() {
  asm volatile("s_waitcnt vmcnt(%0)" :: "n"(N) : "memory");
}
#define LGKM0() asm volatile("s_waitcnt lgkmcnt(0)" ::: "memory")
#define SGB0()  __builtin_amdgcn_sched_barrier(0)
#define FENCE() asm volatile("" ::: "memory")

// plain load; base MUST be wave-uniform (SGPR pair), per-thread offset goes in voff.
template <int OFF> __device__ __forceinline__ void gld(short8& d, uint_t voff, const void* base) {
  asm volatile("global_load_dwordx4 %0, %1, %2 offset:%3"
               : "=v"(d) : "v"(voff), "s"(base), "n"(OFF));
}

// ================= fragment-major layouts (r7-proven) =================
// W3[rb 0..383][kt 0..67][lane][16B], rb = cb*3 + g (cb = 16-col block, g = gate):
//   col c = cb*16 + (lane&15); fused row = [W_hh[g*2048+c] (k<2048) | W_ih[...] | 0]
// A2[mb 0..31][kt 0..67][lane][16B]: lane&15 -> m-row, lane>>4 -> k-quarter.
// F2[kt 0..63][nf 0..4][lane][16B]: fc1 cols j = nf*16 + (lane&15).

__global__ void build_w3(const float* __restrict__ Whh, const float* __restrict__ Wih,
                         ushort_t* __restrict__ W3) {
  int i = blockIdx.x * 256 + threadIdx.x;   // 6528*256 = 1,671,168 = 384*68*64
  int lane = i & 63;
  int kt = (i >> 6) % NKT;
  int rb = i / (64 * NKT);                  // 0..383
  int cb = rb / 3, g = rb - cb * 3;
  int c  = cb * 16 + (lane & 15);
  int gr = g * H + c;
  int k0 = kt * 32 + (lane >> 4) * 8;
  short8 v;
  #pragma unroll
  for (int j = 0; j < 8; ++j) {
    int k = k0 + j;
    float val = 0.f;
    if (k < H) val = Whh[(size_t)gr * H + k];
    else if (k < H + IN) val = Wih[(size_t)gr * IN + (k - H)];
    v[j] = (short)f2bf(val);
  }
  *(short8*)(W3 + (size_t)i * 8) = v;
}

__global__ void build_f2(const float* __restrict__ fc1w, ushort_t* __restrict__ F2) {
  int i = blockIdx.x * 256 + threadIdx.x;   // 80*256 = 20480 = 64*5*64
  int lane = i & 63;
  int ni = (i >> 6) % 5;
  int kt = i / 320;
  int j  = ni * 16 + (lane & 15);
  int k0 = kt * 32 + (lane >> 4) * 8;
  short8 v;
  #pragma unroll
  for (int jj = 0; jj < 8; ++jj) {
    float val = (j < IN) ? fc1w[(size_t)j * H + k0 + jj] : 0.f;
    v[jj] = (short)f2bf(val);
  }
  *(short8*)(F2 + (size_t)i * 8) = v;
}

__global__ void zero_u4(uint4* p, int n) {
  int i = blockIdx.x * 256 + threadIdx.x;
  if (i < n) p[i] = make_uint4(0, 0, 0, 0);
}

__device__ __forceinline__ size_t a2_x_off(int b, int j) {
  int k = 2048 + j;
  int kt = k >> 5, kk = k & 31;
  int mb = b >> 4;
  int ln = (b & 15) | ((kk >> 3) << 4);
  return ((size_t)(mb * NKT + kt) * 64 + ln) * 16 + (kk & 7) * 2;
}

__global__ void fill_x0(const float* __restrict__ enc, char* __restrict__ A2) {
  int i = blockIdx.x * 256 + threadIdx.x;   // 512*69
  int b = i / IN, j = i - b * IN;
  *(ushort_t*)(A2 + a2_x_off(b, j)) = f2bf(enc[(size_t)b * 100 * IN + j]);
}

// ================= fused GRU step (r10: A-relay, no dead SSA) =================
// grid 256: cg = (bid&7)*4 + ((bid>>3)&3) (0..31, 64 cols), mt = bid>>5 (BM=64).
// Wave w: B wave-unique (cb = cg*4+w), issued depth-7 into slot (u+7)&7 — the slot
// consumed this tile (u&7) is never redefined before its MFMA (no dead SSA, no WAR).
// A deduped: wave w loads chunk w (1KB/tile) via voffset, relayed through a 4-slot
// LDS ring. Queue math: issued@tile j = 29+4j; waitv<15> => retired >= 14+4j =
// A(j+1)'s exact position; B(j) (pos <= 4j+1) covered.
__global__ __launch_bounds__(256, 1) void gru_step(
    const char* __restrict__ Aprev, char* __restrict__ Anext,
    const char* __restrict__ W3p, float* __restrict__ h32,
    const float* __restrict__ bih, const float* __restrict__ bhh,
    const float* __restrict__ xsrc, int xstride)
{
  __shared__ short8  Aring[4][4][64];      // 16KB ring: [slot][chunk mi][lane]
  __shared__ ushort_t smh[64][72];         // 9.2KB epilogue transpose
  __shared__ char ldspad[64000];           // push LDS > 80KB -> 1 WG/CU

  const int tid = threadIdx.x;
  const int bid = blockIdx.x;
  const int lane = tid & 63, w = tid >> 6;
  const int l15 = lane & 15, l4 = lane >> 4;
  const int cg = (bid & 7) * 4 + ((bid >> 3) & 3);
  const int mt = bid >> 5;
  const int cb = cg * 4 + w;
  const int c  = cb * 16 + l15;

  if (xstride == -12345) ldspad[tid] = 1;  // opaque keep-alive for the pad

  const float br  = bih[c] + bhh[c];
  const float bz  = bih[H + c] + bhh[H + c];
  const float bin = bih[2 * H + c];
  const float bhn = bhh[2 * H + c];
  // pin biases into regs: no compiler vmem outstanding during the counted pipeline
  asm volatile("" :: "v"(br), "v"(bz), "v"(bin), "v"(bhn));

  const void* ApW = Aprev + (size_t)(mt * 4) * (NKT * 1024);      // wave-uniform base
  uint_t vA  = (uint_t)(w * (NKT * 1024) + lane * 16);            // wave chunk via voffset
  uint_t vB0 = (uint_t)((cb * 3 + 0) * (NKT * 1024) + lane * 16);
  uint_t vB1 = (uint_t)((cb * 3 + 1) * (NKT * 1024) + lane * 16);
  uint_t vB2 = (uint_t)((cb * 3 + 2) * (NKT * 1024) + lane * 16);

  short8 sa[4], fb[8][3];
  short8 fa0, fa1, fa2, fa3;
  float4_t acc[4][4] = {};   // [mi][r, z, gh_n, gi_n]

#define AISS(sl) { gld<0>(sa[sl], vA, ApW); vA += 1024; }
#define BISS(sl) { gld<0>(fb[sl][0], vB0, W3p); gld<0>(fb[sl][1], vB1, W3p); \
                   gld<0>(fb[sl][2], vB2, W3p); vB0 += 1024; vB1 += 1024; vB2 += 1024; }
#define MFMA3(mi, fav, j, G2) \
  acc[mi][0]  = MFMA_BF16(fav, fb[j][0], acc[mi][0], 0, 0, 0); \
  acc[mi][1]  = MFMA_BF16(fav, fb[j][1], acc[mi][1], 0, 0, 0); \
  acc[mi][G2] = MFMA_BF16(fav, fb[j][2], acc[mi][G2], 0, 0, 0);
#define MFMA12(j, G2) MFMA3(0, fa0, j, G2) MFMA3(1, fa1, j, G2) \
                      MFMA3(2, fa2, j, G2) MFMA3(3, fa3, j, G2)
#define RDFA(slot) \
  FENCE(); \
  fa0 = Aring[slot][0][lane]; fa1 = Aring[slot][1][lane]; \
  fa2 = Aring[slot][2][lane]; fa3 = Aring[slot][3][lane];

// steady tile j (u=j&7): issue A(j+4) into sa[j&3] (old A(j) consumed at tile j-1),
// issue B(j+7) into fb[(u+7)&7] (old B(j-1) consumed at tile j-1); waitv<15> retires
// exactly A(j+1); relay-write it; barrier; read A(j) frags; MFMA with fb[u] = B(j).
#define GRUT(u, G2) \
  AISS((u + 4) & 3) BISS((u + 7) & 7) \
  waitv<15>(); SGB0(); \
  Aring[(u + 1) & 3][w][lane] = sa[(u + 1) & 3]; \
  LGKM0(); \
  __builtin_amdgcn_s_barrier(); \
  RDFA(u & 3) \
  LGKM0(); SGB0(); \
  MFMA12(u, G2)

// tail: A-issue only (tiles 61..63)
#define GRUTA(u, NW) \
  AISS((u + 4) & 3) \
  waitv<NW>(); SGB0(); \
  Aring[(u + 1) & 3][w][lane] = sa[(u + 1) & 3]; \
  LGKM0(); \
  __builtin_amdgcn_s_barrier(); \
  RDFA(u & 3) \
  LGKM0(); SGB0(); \
  MFMA12(u, 2)

// tail: no issue, with/without relay-write (tiles 64..67)
#define GRUTN_W(u, NW, G2) \
  waitv<NW>(); SGB0(); \
  Aring[(u + 1) & 3][w][lane] = sa[(u + 1) & 3]; \
  LGKM0(); \
  __builtin_amdgcn_s_barrier(); \
  RDFA(u & 3) \
  LGKM0(); SGB0(); \
  MFMA12(u, G2)
#define GRUTN_NW(u, NW, G2) \
  waitv<NW>(); SGB0(); \
  LGKM0(); \
  __builtin_amdgcn_s_barrier(); \
  RDFA(u & 3) \
  LGKM0(); SGB0(); \
  MFMA12(u, G2)

  // ---- prologue: A0..A3 + B0..B6 in flight (25 loads); pre-relay A0 ----
  AISS(0) AISS(1) AISS(2) AISS(3)
  BISS(0) BISS(1) BISS(2) BISS(3) BISS(4) BISS(5) BISS(6)
  waitv<24>(); SGB0();                 // retire exactly A0
  Aring[0][w][lane] = sa[0];
  LGKM0();
  __builtin_amdgcn_s_barrier();

  // ---- steady: tiles 0..55 ----
  #pragma unroll 1
  for (int g8 = 0; g8 < 7; ++g8) {
    GRUT(0, 2) GRUT(1, 2) GRUT(2, 2) GRUT(3, 2)
    GRUT(4, 2) GRUT(5, 2) GRUT(6, 2) GRUT(7, 2)
  }
  // tiles 56..60 (full issues: A60..64, B63..67)
  GRUT(0, 2) GRUT(1, 2) GRUT(2, 2) GRUT(3, 2) GRUT(4, 2)
  // tiles 61..63 (A65..67 issues only; waits: 270-12=258=A62, 271-9=262=A63, 272-6=266=A64)
  GRUTA(5, 12) GRUTA(6, 9) GRUTA(7, 6)
  // tiles 64..67: x-part -> gi_n (G2=3); waits retire A65(270), A66(271), A67(272), B67
  GRUTN_W(0, 2, 3) GRUTN_W(1, 1, 3) GRUTN_W(2, 0, 3) GRUTN_NW(3, 0, 3)
  // vmcnt == 0 and lgkm == 0: nothing outstanding can clobber reused registers.

  // ---- epilogue: gates fp32, fp32 carry; h' -> LDS transpose -> 16B stores ----
  #pragma unroll
  for (int mi = 0; mi < 4; ++mi) {
    #pragma unroll
    for (int r4 = 0; r4 < 4; ++r4) {
      int m = mt * 64 + mi * 16 + l4 * 4 + r4;
      float rg = 1.f / (1.f + __expf(-(acc[mi][0][r4] + br)));
      float zg = 1.f / (1.f + __expf(-(acc[mi][1][r4] + bz)));
      float ng = tanhf(acc[mi][3][r4] + bin + rg * (acc[mi][2][r4] + bhn));
      float hold = h32[(size_t)m * H + c];
      float hn = (1.f - zg) * ng + zg * hold;
      h32[(size_t)m * H + c] = hn;
      smh[mi * 16 + l4 * 4 + r4][w * 16 + l15] = f2bf(hn);
    }
  }
  __syncthreads();
  #pragma unroll
  for (int e = 0; e < 2; ++e) {
    int cid = tid * 2 + e;                 // 512 chunks: (m 0..63) x (ktrel 0..1) x (khi 0..3)
    int m = cid >> 3, ktrel = (cid >> 2) & 1, khi = cid & 3;
    short8 v = *(const short8*)&smh[m][ktrel * 32 + khi * 8];
    int m_abs = mt * 64 + m;
    int mb2 = m_abs >> 4;
    int ln = (m_abs & 15) | (khi << 4);
    int kt = cg * 2 + ktrel;
    *(short8*)(Anext + ((size_t)(mb2 * NKT + kt) * 64 + ln) * 16) = v;
  }
  // encoder next-x feed (8 WGs with cg==0: mt 0..7 cover all 512 rows)
  if ((bid & 31) == 0 && xsrc != nullptr) {
    for (int i = tid; i < 64 * IN; i += 256) {
      int rr = i / IN, cc = i - rr * IN;
      int m = mt * 64 + rr;
      *(ushort_t*)(Anext + a2_x_off(m, cc)) = f2bf(xsrc[(size_t)m * xstride + cc]);
    }
  }
}

// ================= decoder output step (r7-proven, unchanged) =================
__global__ __launch_bounds__(256, 1) void out_step(
    char* __restrict__ Acat, const char* __restrict__ F2p,
    const float* __restrict__ fc1b, const float* __restrict__ inp,
    float* __restrict__ outp)
{
  __shared__ float4_t redf[4 * 5 * 64];    // 20KB
  const int tid = threadIdx.x;
  const int mb = blockIdx.x;               // 0..31
  const int lane = tid & 63, w = tid >> 6;
  const int l15 = lane & 15, l4 = lane >> 4;

  const void* F2b = (const char*)F2p + 4096;   // imm offset max 4095 -> second base
  uint_t voA = (uint_t)((mb * NKT + w * 16) * 1024 + lane * 16);
  uint_t vf  = (uint_t)((w * 16) * 5120 + lane * 16);

  short8 da[8], db[8][5];
  float4_t oa[5] = {};

#define DPRO(sl) \
  gld<0>(da[sl], voA, Acat); \
  gld<0>(db[sl][0], vf, F2p); gld<1024>(db[sl][1], vf, F2p); \
  gld<2048>(db[sl][2], vf, F2p); gld<3072>(db[sl][3], vf, F2p); \
  gld<0>(db[sl][4], vf, F2b); \
  voA += 1024; vf += 5120;
#define DMM(sl) \
  { _Pragma("unroll") for (int nf = 0; nf < 5; ++nf) \
      oa[nf] = MFMA_BF16(da[sl], db[sl][nf], oa[nf], 0, 0, 0); }

  DPRO(0) DPRO(1) DPRO(2) DPRO(3) DPRO(4) DPRO(5) DPRO(6) DPRO(7)
  waitv<42>(); SGB0(); DMM(0) DPRO(0)
  waitv<42>(); SGB0(); DMM(1) DPRO(1)
  waitv<42>(); SGB0(); DMM(2) DPRO(2)
  waitv<42>(); SGB0(); DMM(3) DPRO(3)
  waitv<42>(); SGB0(); DMM(4) DPRO(4)
  waitv<42>(); SGB0(); DMM(5) DPRO(5)
  waitv<42>(); SGB0(); DMM(6) DPRO(6)
  waitv<42>(); SGB0(); DMM(7) DPRO(7)
  waitv<42>(); SGB0(); DMM(0)
  waitv<36>(); SGB0(); DMM(1)
  waitv<30>(); SGB0(); DMM(2)
  waitv<24>(); SGB0(); DMM(3)
  waitv<18>(); SGB0(); DMM(4)
  waitv<12>(); SGB0(); DMM(5)
  waitv<6>();  SGB0(); DMM(6)
  waitv<0>();  SGB0(); DMM(7)
  // vmcnt == 0: pipeline fully drained before register reuse below.

  #pragma unroll
  for (int nf = 0; nf < 5; ++nf) redf[(w * 5 + nf) * 64 + lane] = oa[nf];
  __syncthreads();

  #pragma unroll 1
  for (int pass = 0; pass < 2; ++pass) {
    if (pass == 1 && w != 0) break;
    const int nf = pass ? 4 : w;
    float4_t sum = redf[(0 * 5 + nf) * 64 + lane] + redf[(1 * 5 + nf) * 64 + lane]
                 + redf[(2 * 5 + nf) * 64 + lane] + redf[(3 * 5 + nf) * 64 + lane];
    int j = nf * 16 + l15;
    if (j < IN) {
      float bj = fc1b[j];
      #pragma unroll
      for (int r4 = 0; r4 < 4; ++r4) {
        int m = mb * 16 + l4 * 4 + r4;
        float v = sum[r4] + bj + inp[(size_t)m * (TGT * IN) + j];
        outp[(size_t)m * (TGT * IN) + j] = v;
        *(ushort_t*)(Acat + a2_x_off(m, j)) = f2bf(v);   // next decoder input
      }
    }
  }
}

// ================= launch =================
extern "C" void kernel_launch(void* const* d_in, const int* in_sizes, int n_in,
                              void* d_out, int out_size, void* d_ws, size_t ws_size,
                              hipStream_t stream) {
  const float* enc  = (const float*)d_in[0];
  const float* dec  = (const float*)d_in[1];
  const float* Wih  = (const float*)d_in[2];
  const float* Whh  = (const float*)d_in[3];
  const float* b_ih = (const float*)d_in[4];
  const float* b_hh = (const float*)d_in[5];
  const float* fc1w = (const float*)d_in[6];
  const float* fc1b = (const float*)d_in[7];
  float* out = (float*)d_out;

  char* ws = (char*)d_ws;
  ushort_t* W3  = (ushort_t*)ws;                    // 384*68*64*16 = 26,738,688
  char*     A0  = ws + 26738688;                    // 2,228,224
  char*     A1  = ws + 28966912;                    // 2,228,224
  float*    h32 = (float*)(ws + 31195136);          // 4,194,304
  ushort_t* F2  = (ushort_t*)(ws + 35389440);       // 327,680
  char* A2[2] = {A0, A1};

  build_w3<<<6528, 256, 0, stream>>>(Whh, Wih, W3);
  zero_u4<<<2112, 256, 0, stream>>>((uint4*)A0, 540672);   // A0 + A1 + h32
  fill_x0<<<138, 256, 0, stream>>>(enc, A0);
  build_f2<<<80, 256, 0, stream>>>(fc1w, F2);

  for (int t = 0; t < 149; ++t) {
    const float* xsrc = nullptr; int xstride = 0;
    if (t < 98)       { xsrc = enc + (size_t)(t + 1) * IN; xstride = 100 * IN; }
    else if (t == 98) { xsrc = dec;                        xstride = TGT * IN; }
    gru_step<<<256, 256, 0, stream>>>(A2[t & 1], A2[(t + 1) & 1], (const char*)W3, h32,
                                      b_ih, b_hh, xsrc, xstride);
    if (t >= 99) {
      int d = t - 99;
      const float* inp = (d == 0) ? dec : out + (size_t)(d - 1) * IN;
      out_step<<<32, 256, 0, stream>>>(A2[(t + 1) & 1], (const char*)F2, fc1b, inp,
                                       out + (size_t)d * IN);
    }
  }
}